// Round 4
// baseline (93.208 us; speedup 1.0000x reference)
//
#include <hip/hip_runtime.h>
#include <math.h>

#define BB 32
#define CC 512      // = L (sequence length)
#define HW 4096
#define DM 32       // d_model
#define DI 32       // d_inner
#define DS 8        // d_state
#define KC 4        // conv kernel

#define NCH 16      // chunks per (b,dir)
#define CHL 32      // chunk length

__device__ __forceinline__ float siluf(float x) {
    return x / (1.0f + __expf(-x));
}
__device__ __forceinline__ float softplusf(float x) {
    float ax = fabsf(x);
    return fmaxf(x, 0.0f) + log1pf(__expf(-ax));
}

// ---- Kernel 1: avg+max pool over H*W=4096 FUSED with lin1+LN+in_proj -> xz ----
// block = one (b, c=l); 256 threads.
__global__ __launch_bounds__(256) void poolproj_kernel(
    const float* __restrict__ x,
    const float* __restrict__ lin1_w, const float* __restrict__ lin1_b,
    const float* __restrict__ ln1_g, const float* __restrict__ ln1_b,
    const float* __restrict__ in_proj_w, float* __restrict__ xz)
{
    int bc = blockIdx.x;                       // b*512 + l
    int b = bc >> 9, l = bc & 511;
    const float4* xp = reinterpret_cast<const float4*>(x + (size_t)bc * HW);
    int tid = threadIdx.x;

    __shared__ float sWp[64][33];   // in_proj_w padded (bank-conflict-free dot)
    __shared__ float ss[4], sm[4];
    __shared__ float h_s[DM];

    float s = 0.f, m = -INFINITY;
#pragma unroll
    for (int r = 0; r < 4; ++r) {
        float4 v = xp[r * 256 + tid];
        s += (v.x + v.y) + (v.z + v.w);
        m = fmaxf(m, fmaxf(fmaxf(v.x, v.y), fmaxf(v.z, v.w)));
    }
    // stage in_proj weights while loads drain
    for (int i = tid; i < 64 * DM; i += 256) sWp[i >> 5][i & 31] = in_proj_w[i];

    for (int off = 32; off > 0; off >>= 1) {
        s += __shfl_down(s, off);
        m = fmaxf(m, __shfl_down(m, off));
    }
    int wave = tid >> 6;
    if ((tid & 63) == 0) { ss[wave] = s; sm[wave] = m; }
    __syncthreads();

    // lanes 0..31 (wave 0): lin1 + layernorm across the 32-lane group
    if (tid < 32) {
        float S = (ss[0] + ss[1]) + (ss[2] + ss[3]);
        float M = fmaxf(fmaxf(sm[0], sm[1]), fmaxf(sm[2], sm[3]));
        float a = S * (1.0f / HW);
        int m_ = tid;
        float h = a * lin1_w[2 * m_] + M * lin1_w[2 * m_ + 1] + lin1_b[m_];
        float sum = h;
#pragma unroll
        for (int mask = 1; mask < 32; mask <<= 1) sum += __shfl_xor(sum, mask);
        float mean = sum * (1.0f / DM);
        float d = h - mean;
        float vs = d * d;
#pragma unroll
        for (int mask = 1; mask < 32; mask <<= 1) vs += __shfl_xor(vs, mask);
        float rs = rsqrtf(vs * (1.0f / DM) + 1e-5f);
        h_s[m_] = d * rs * ln1_g[m_] + ln1_b[m_];
    }
    __syncthreads();

    // lanes 0..63: in_proj rows
    if (tid < 64) {
        int e = tid;
        float acc = 0.f;
#pragma unroll
        for (int m_ = 0; m_ < DM; ++m_) acc += h_s[m_] * sWp[e][m_];
        xz[(((size_t)b * 64 + e) << 9) + l] = acc;
    }
}

// ------- Kernel 2: conv1d + silu + x_proj + dtproj + scan PHASE 1 (chunk carries) -------
// grid = (b,dir) x 16 chunks of 32 scan positions; block = 256 threads.
__global__ __launch_bounds__(256) void convscan1_kernel(
    const float* __restrict__ xz,
    const float* __restrict__ conv_w_f, const float* __restrict__ conv_b_f,
    const float* __restrict__ xproj_w_f, const float* __restrict__ dtproj_w_f,
    const float* __restrict__ dtproj_b_f,
    const float* __restrict__ conv_w_r, const float* __restrict__ conv_b_r,
    const float* __restrict__ xproj_w_r, const float* __restrict__ dtproj_w_r,
    const float* __restrict__ dtproj_b_r,
    const float* __restrict__ A_log_f, const float* __restrict__ A_log_r,
    float* __restrict__ u_g, float* __restrict__ dt_g,
    float* __restrict__ B_g, float* __restrict__ C_g,
    float* __restrict__ carrA, float* __restrict__ carrH)
{
    int bx = blockIdx.x;
    int bd = bx >> 4, j = bx & 15;      // (b,dir), chunk 0..15
    int b = bd >> 1, dir = bd & 1;
    int tid = threadIdx.x;
    const float* cw = dir ? conv_w_r : conv_w_f;
    const float* cb = dir ? conv_b_r : conv_b_f;
    const float* xw = dir ? xproj_w_r : xproj_w_f;
    const float* dw = dir ? dtproj_w_r : dtproj_w_f;
    const float* db = dir ? dtproj_b_r : dtproj_b_f;
    const float* Alog = dir ? A_log_r : A_log_f;
    const float* xzb = xz + (size_t)b * 64 * 512;   // x-half rows 0..31

    __shared__ float xt[32][39];        // scan cols j*32-3 .. j*32+31 (35 used)
    __shared__ float xw_s[18][33];
    __shared__ float u_s[CHL][33];
    __shared__ float dt_s[CHL][33];
    __shared__ float B_s[CHL][9];
    __shared__ float C_s[CHL][9];
    __shared__ float dtr_s[CHL][2];

    // stage xz tile (scan order, zero-pad before scan pos 0) + xproj weights
    for (int idx = tid; idx < 32 * 35; idx += 256) {
        int dd = idx / 35, t = idx - dd * 35;
        int sidx = j * CHL - 3 + t;
        float v = 0.f;
        if (sidx >= 0) {
            int orig = dir ? (511 - sidx) : sidx;
            v = xzb[(dd << 9) + orig];
        }
        xt[dd][t] = v;
    }
    for (int idx = tid; idx < 18 * 32; idx += 256)
        xw_s[idx >> 5][idx & 31] = xw[idx];
    __syncthreads();

    // conv + silu -> u_s  (thread = (l, 4-d group))
    int l = tid >> 3, g8 = tid & 7;
#pragma unroll
    for (int i = 0; i < 4; ++i) {
        int dd = g8 * 4 + i;
        float acc = cb[dd];
#pragma unroll
        for (int k = 0; k < KC; ++k) acc += cw[dd * KC + k] * xt[dd][l + k];
        u_s[l][dd] = siluf(acc);
    }
    __syncthreads();

    // projections: 18 outputs per l (2 dt-rank, 8 B, 8 C)
    for (int o = g8; o < 18; o += 8) {
        float acc = 0.f;
#pragma unroll
        for (int m_ = 0; m_ < 32; ++m_) acc += u_s[l][m_] * xw_s[o][m_];
        if (o < 2) dtr_s[l][o] = acc;
        else if (o < 10) B_s[l][o - 2] = acc;
        else             C_s[l][o - 10] = acc;
    }
    __syncthreads();

    // dt = softplus(dtproj); coalesced global writes of u/dt/B/C
    size_t rowbase = ((size_t)bd * 512 + j * CHL) * 32;
    for (int idx = tid; idx < CHL * 32; idx += 256) {
        int ll = idx >> 5, dd = idx & 31;
        float v = dtr_s[ll][0] * dw[dd * 2] + dtr_s[ll][1] * dw[dd * 2 + 1] + db[dd];
        float sp = softplusf(v);
        dt_s[ll][dd] = sp;
        dt_g[rowbase + idx] = sp;
        u_g[rowbase + idx] = u_s[ll][dd];
    }
    size_t base8 = ((size_t)bd * 512 + j * CHL) * 8;
    if (tid < CHL * 8) {
        B_g[base8 + tid] = B_s[tid >> 3][tid & 7];
        C_g[base8 + tid] = C_s[tid >> 3][tid & 7];
    }
    __syncthreads();

    // phase-1 local scan: thread = (d, n)
    int dd = tid >> 3, nn = tid & 7;
    float Aa = -__expf(Alog[tid]);      // Alog[dd*8+nn] == Alog[tid]
    float ap = 1.f, h = 0.f;
#pragma unroll 4
    for (int sl = 0; sl < CHL; ++sl) {
        float dtv = dt_s[sl][dd];
        float uu  = u_s[sl][dd];
        float bm  = B_s[sl][nn];
        float dA  = __expf(dtv * Aa);
        ap *= dA;
        h = dA * h + dtv * uu * bm;
    }
    carrA[((size_t)bx << 8) + tid] = ap;
    carrH[((size_t)bx << 8) + tid] = h;
}

// ------- Kernel 3: carry combine + scan PHASE 3 + gate + out_proj + LN + head -------
// grid = b x 16 original-l tiles of 32. Forward chunk t and reverse chunk 15-t cover
// the SAME original l range -> one block does both dirs and the final head.
// block = 128 threads = (dir, d, n-half); each thread owns 4 n-states.
__global__ __launch_bounds__(128) void scan2final_kernel(
    const float* __restrict__ u_g, const float* __restrict__ dt_g,
    const float* __restrict__ B_g, const float* __restrict__ C_g,
    const float* __restrict__ carrA, const float* __restrict__ carrH,
    const float* __restrict__ A_log_f, const float* __restrict__ D_f,
    const float* __restrict__ A_log_r, const float* __restrict__ D_r,
    const float* __restrict__ xz,
    const float* __restrict__ out_proj_w, const float* __restrict__ mnorm_g,
    const float* __restrict__ mnorm_b, const float* __restrict__ lin2_w,
    const float* __restrict__ lin2_b, float* __restrict__ out)
{
    int bx = blockIdx.x;
    int b = bx >> 4, t = bx & 15;       // batch, original l-tile
    int tid = threadIdx.x;
    int dir = tid >> 6;                 // 0..1
    int r = tid & 63;
    int dd = r >> 1, nh = r & 1, n0 = nh * 4;
    int bd = b * 2 + dir;
    int tt = dir ? (15 - t) : t;        // this dir's chunk covering the tile

    const float* Alog = dir ? A_log_r : A_log_f;
    const float* Dp   = dir ? D_r : D_f;

    float A0 = -__expf(Alog[dd * 8 + n0 + 0]);
    float A1 = -__expf(Alog[dd * 8 + n0 + 1]);
    float A2 = -__expf(Alog[dd * 8 + n0 + 2]);
    float A3 = -__expf(Alog[dd * 8 + n0 + 3]);
    float Dd = Dp[dd];

    // combine carries of preceding chunks -> exact prefix state
    float h0 = 0.f, h1 = 0.f, h2 = 0.f, h3 = 0.f;
    for (int jj = 0; jj < tt; ++jj) {
        size_t cbase = (((size_t)bd * NCH + jj) << 8) + dd * 8 + n0;
        float4 av = *reinterpret_cast<const float4*>(carrA + cbase);
        float4 hv = *reinterpret_cast<const float4*>(carrH + cbase);
        h0 = av.x * h0 + hv.x;
        h1 = av.y * h1 + hv.y;
        h2 = av.z * h2 + hv.z;
        h3 = av.w * h3 + hv.w;
    }

    __shared__ float y_s[2][2][CHL][33];

    size_t sb = (size_t)bd * 512 + tt * CHL;
#pragma unroll 4
    for (int sl = 0; sl < CHL; ++sl) {
        size_t s32 = (sb + sl) * 32 + dd;
        float dtv = dt_g[s32];
        float uu  = u_g[s32];
        float4 Bv = *reinterpret_cast<const float4*>(B_g + (sb + sl) * 8 + n0);
        float4 Cv = *reinterpret_cast<const float4*>(C_g + (sb + sl) * 8 + n0);
        float dtu = dtv * uu;
        h0 = __expf(dtv * A0) * h0 + dtu * Bv.x;
        h1 = __expf(dtv * A1) * h1 + dtu * Bv.y;
        h2 = __expf(dtv * A2) * h2 + dtu * Bv.z;
        h3 = __expf(dtv * A3) * h3 + dtu * Bv.w;
        float py = h0 * Cv.x + h1 * Cv.y + h2 * Cv.z + h3 * Cv.w;
        if (nh == 0) py += Dd * uu;
        int ll = dir ? (CHL - 1 - sl) : sl;  // position within original tile
        y_s[dir][nh][ll][dd] = py;
    }
    __syncthreads();

    // final head: thread = one original l within the tile
    if (tid < CHL) {
        int lo = t * CHL + tid;
        float comb[DI];
#pragma unroll
        for (int d2 = 0; d2 < DI; ++d2) {
            float ys = y_s[0][0][tid][d2] + y_s[0][1][tid][d2]
                     + y_s[1][0][tid][d2] + y_s[1][1][tid][d2];
            float z = xz[(((size_t)(b * 64 + 32 + d2)) << 9) + lo];
            comb[d2] = 0.5f * ys * siluf(z);
        }
        float o[DM];
        float mean = 0.f;
#pragma unroll
        for (int oo = 0; oo < DM; ++oo) {
            float acc = 0.f;
#pragma unroll
            for (int d2 = 0; d2 < DI; ++d2) acc += comb[d2] * out_proj_w[oo * DI + d2];
            o[oo] = acc;
            mean += acc;
        }
        mean *= (1.0f / DM);
        float var = 0.f;
#pragma unroll
        for (int oo = 0; oo < DM; ++oo) { float df = o[oo] - mean; var += df * df; }
        var *= (1.0f / DM);
        float rs = rsqrtf(var + 1e-5f);
        float s = lin2_b[0];
#pragma unroll
        for (int oo = 0; oo < DM; ++oo) {
            float v = (o[oo] - mean) * rs * mnorm_g[oo] + mnorm_b[oo];
            s += v * lin2_w[oo];
        }
        float att = 1.0f / (1.0f + __expf(-s));
        out[(size_t)b * 512 + lo] = 0.25f * att + 0.875f;
    }
}

extern "C" void kernel_launch(void* const* d_in, const int* in_sizes, int n_in,
                              void* d_out, int out_size, void* d_ws, size_t ws_size,
                              hipStream_t stream)
{
    const float* x         = (const float*)d_in[0];
    const float* lin1_w    = (const float*)d_in[1];
    const float* lin1_b    = (const float*)d_in[2];
    const float* ln1_g     = (const float*)d_in[3];
    const float* ln1_b     = (const float*)d_in[4];
    const float* in_proj_w = (const float*)d_in[5];
    const float* conv_w_f  = (const float*)d_in[6];
    const float* conv_b_f  = (const float*)d_in[7];
    const float* xproj_w_f = (const float*)d_in[8];
    const float* dtproj_w_f= (const float*)d_in[9];
    const float* dtproj_b_f= (const float*)d_in[10];
    const float* A_log_f   = (const float*)d_in[11];
    const float* D_f       = (const float*)d_in[12];
    const float* conv_w_r  = (const float*)d_in[13];
    const float* conv_b_r  = (const float*)d_in[14];
    const float* xproj_w_r = (const float*)d_in[15];
    const float* dtproj_w_r= (const float*)d_in[16];
    const float* dtproj_b_r= (const float*)d_in[17];
    const float* A_log_r   = (const float*)d_in[18];
    const float* D_r       = (const float*)d_in[19];
    const float* out_proj_w= (const float*)d_in[20];
    const float* mnorm_g   = (const float*)d_in[21];
    const float* mnorm_b   = (const float*)d_in[22];
    const float* lin2_w    = (const float*)d_in[23];
    const float* lin2_b    = (const float*)d_in[24];

    float* ws   = (float*)d_ws;
    float* xz   = ws;                          // 32*64*512   = 1048576
    float* u_g  = xz + 1048576;                // 2*32*512*32 = 1048576
    float* dt_g = u_g + 1048576;               // 1048576
    float* B_g  = dt_g + 1048576;              // 2*32*512*8  = 262144
    float* C_g  = B_g + 262144;                // 262144
    float* carrA= C_g + 262144;                // 64*16*256   = 262144
    float* carrH= carrA + 262144;              // 262144
    (void)ws_size; (void)in_sizes; (void)n_in; (void)out_size;

    poolproj_kernel<<<BB * CC, 256, 0, stream>>>(x, lin1_w, lin1_b, ln1_g, ln1_b, in_proj_w, xz);
    convscan1_kernel<<<BB * 2 * NCH, 256, 0, stream>>>(
        xz, conv_w_f, conv_b_f, xproj_w_f, dtproj_w_f, dtproj_b_f,
        conv_w_r, conv_b_r, xproj_w_r, dtproj_w_r, dtproj_b_r,
        A_log_f, A_log_r, u_g, dt_g, B_g, C_g, carrA, carrH);
    scan2final_kernel<<<BB * NCH, 128, 0, stream>>>(
        u_g, dt_g, B_g, C_g, carrA, carrH,
        A_log_f, D_f, A_log_r, D_r, xz,
        out_proj_w, mnorm_g, mnorm_b, lin2_w, lin2_b, (float*)d_out);
}